// Round 1
// baseline (122.591 us; speedup 1.0000x reference)
//
#include <hip/hip_runtime.h>
#include <math.h>

// SegmentCausalCrossAttentionFlex on MI355X (gfx950)
// B=2, LQ=4096, LK=512, Q_DIM=KV_DIM=D_ATTN=1024, H=16, HD=64, LOOKBACK=4
// Pipeline: f32->bf16 casts, W transposes, rope tables,
//           GEMM1 (q@Wq + RoPE + 1/8 scale), GEMM2 (kv@Wkv + RoPE on K half),
//           sparse 5-key attention, GEMM3 (ctx@Wo -> f32 out).

typedef unsigned short u16;
typedef __attribute__((ext_vector_type(8))) short bhalf8;   // 8 x bf16 (MFMA A/B frag)
typedef __attribute__((ext_vector_type(4))) float fvec4;    // MFMA C/D frag

__device__ __forceinline__ u16 f2bf(float f) {
  unsigned u = __float_as_uint(f);
  u += 0x7fffu + ((u >> 16) & 1u);      // round-to-nearest-even
  return (u16)(u >> 16);
}
__device__ __forceinline__ float bf2f(u16 h) {
  return __uint_as_float(((unsigned)h) << 16);
}

// ---------------------------------------------------------------------------
// f32 -> bf16 elementwise (vectorized float4 loads)
__global__ __launch_bounds__(256) void f32_to_bf16_kernel(
    const float* __restrict__ in, u16* __restrict__ out, int n4) {
  int idx = blockIdx.x * blockDim.x + threadIdx.x;
  int stride = gridDim.x * blockDim.x;
  for (int i = idx; i < n4; i += stride) {
    const float4 v = ((const float4*)in)[i];
    ushort4 o;
    o.x = f2bf(v.x); o.y = f2bf(v.y); o.z = f2bf(v.z); o.w = f2bf(v.w);
    ((ushort4*)out)[i] = o;
  }
}

// ---------------------------------------------------------------------------
// W [K][N] f32 -> Wt [N][K] bf16 (LDS transpose, padded)
__global__ __launch_bounds__(256) void transpose_w_kernel(
    const float* __restrict__ W, u16* __restrict__ Wt, int K, int N) {
  __shared__ float tile[32][33];
  const int n0 = blockIdx.x * 32, k0 = blockIdx.y * 32;
  const int tx = threadIdx.x, ty = threadIdx.y;   // block (32,8)
#pragma unroll
  for (int i = 0; i < 32; i += 8)
    tile[ty + i][tx] = W[(size_t)(k0 + ty + i) * N + n0 + tx];
  __syncthreads();
#pragma unroll
  for (int i = 0; i < 32; i += 8)
    Wt[(size_t)(n0 + ty + i) * K + k0 + tx] = f2bf(tile[tx][ty + i]);
}

// ---------------------------------------------------------------------------
// RoPE tables: cos/sin[pos][j], pos in [0,8192), j in [0,32)
// inv_freq[j] = 10000^(-j/32);  angle = pos * inv_freq[j]
__global__ __launch_bounds__(256) void rope_table_kernel(
    float* __restrict__ cosT, float* __restrict__ sinT) {
  const int idx = blockIdx.x * 256 + threadIdx.x;   // 8192*32 total
  const int pos = idx >> 5, j = idx & 31;
  const float invf = expf(-(float)j * 0.28782313662425572f);  // ln(10000)/32
  const float a = (float)pos * invf;
  float s, c;
  sincosf(a, &s, &c);
  cosT[idx] = c;
  sinT[idx] = s;
}

// ---------------------------------------------------------------------------
// Core 128x128 GEMM tile: C += A[M,K] * Bt[N,K]^T, bf16 in, f32 acc.
// 4 waves (2x2), each computes 64x64 = 4x4 fragments of 16x16 (mfma 16x16x32).
// LDS linear [128 rows][32 k] with 16B-chunk XOR swizzle: chunk slot
// s = g ^ ((row>>1)&3). K-order inside the tile is a consistent bijection for
// both operands (contiguous k=g*8+e), which MFMA contraction is invariant to.
__device__ __forceinline__ void gemm_core_128(
    const u16* __restrict__ A, const u16* __restrict__ Bt, int K,
    int m0, int n0, fvec4 acc[4][4], u16* As, u16* Bs) {
  const int tid = threadIdx.x;
  const int lane = tid & 63;
  const int wv = tid >> 6;
  const int wm = wv >> 1, wn = wv & 1;

  int a_off[4], b_off[4];
#pragma unroll
  for (int i = 0; i < 4; ++i) {
    const int rA = wm * 64 + i * 16 + (lane & 15);
    a_off[i] = rA * 32 + (((lane >> 4) ^ ((rA >> 1) & 3)) << 3);
    const int rB = wn * 64 + i * 16 + (lane & 15);
    b_off[i] = rB * 32 + (((lane >> 4) ^ ((rB >> 1) & 3)) << 3);
  }
  const int i0 = tid, i1 = tid + 256;
  const int r0 = i0 >> 2, g0 = (i0 & 3) ^ ((r0 >> 1) & 3);
  const int r1 = i1 >> 2, g1 = (i1 & 3) ^ ((r1 >> 1) & 3);
  const size_t sK = (size_t)K;
  const u16* a0 = A + (size_t)(m0 + r0) * sK + g0 * 8;
  const u16* a1 = A + (size_t)(m0 + r1) * sK + g1 * 8;
  const u16* b0 = Bt + (size_t)(n0 + r0) * sK + g0 * 8;
  const u16* b1 = Bt + (size_t)(n0 + r1) * sK + g1 * 8;

  for (int k0 = 0; k0 < K; k0 += 32) {
    __builtin_amdgcn_global_load_lds(
        (__attribute__((address_space(1))) void*)(a0 + k0),
        (__attribute__((address_space(3))) void*)(As + i0 * 8), 16, 0, 0);
    __builtin_amdgcn_global_load_lds(
        (__attribute__((address_space(1))) void*)(a1 + k0),
        (__attribute__((address_space(3))) void*)(As + i1 * 8), 16, 0, 0);
    __builtin_amdgcn_global_load_lds(
        (__attribute__((address_space(1))) void*)(b0 + k0),
        (__attribute__((address_space(3))) void*)(Bs + i0 * 8), 16, 0, 0);
    __builtin_amdgcn_global_load_lds(
        (__attribute__((address_space(1))) void*)(b1 + k0),
        (__attribute__((address_space(3))) void*)(Bs + i1 * 8), 16, 0, 0);
    __syncthreads();
    bhalf8 af[4], bfv[4];
#pragma unroll
    for (int i = 0; i < 4; ++i) af[i] = *(const bhalf8*)(As + a_off[i]);
#pragma unroll
    for (int i = 0; i < 4; ++i) bfv[i] = *(const bhalf8*)(Bs + b_off[i]);
#pragma unroll
    for (int mi = 0; mi < 4; ++mi)
#pragma unroll
      for (int ni = 0; ni < 4; ++ni)
        acc[mi][ni] = __builtin_amdgcn_mfma_f32_16x16x32_bf16(
            af[mi], bfv[ni], acc[mi][ni], 0, 0, 0);
    __syncthreads();
  }
}

#define GEMM_PROLOGUE()                                              \
  __shared__ __align__(16) u16 As[128 * 32];                         \
  __shared__ __align__(16) u16 Bs[128 * 32];                         \
  fvec4 acc[4][4];                                                   \
  _Pragma("unroll") for (int i = 0; i < 4; ++i)                      \
      _Pragma("unroll") for (int j = 0; j < 4; ++j)                  \
          acc[i][j] = (fvec4){0.f, 0.f, 0.f, 0.f};

// ---------------------------------------------------------------------------
// GEMM1: qh = bf16( RoPE(q @ Wq) * 0.125 )   M=8192 N=1024 K=1024
__global__ __launch_bounds__(256) void gemm_qh_kernel(
    const u16* __restrict__ A, const u16* __restrict__ Bt,
    u16* __restrict__ qh, const int* __restrict__ pos_ids,
    const float* __restrict__ cosT, const float* __restrict__ sinT) {
  GEMM_PROLOGUE();
  const int mb = blockIdx.x >> 3, nb = blockIdx.x & 7;
  const int m0 = mb * 128, n0 = nb * 128;
  gemm_core_128(A, Bt, 1024, m0, n0, acc, As, Bs);
  const int lane = threadIdx.x & 63;
  const int wv = threadIdx.x >> 6, wm = wv >> 1, wn = wv & 1;
#pragma unroll
  for (int mi = 0; mi < 4; ++mi) {
#pragma unroll
    for (int r = 0; r < 4; ++r) {
      const int rowg = m0 + wm * 64 + mi * 16 + (lane >> 4) * 4 + r;
      int pos = pos_ids[rowg];
      pos = pos < 0 ? 0 : (pos > 8191 ? 8191 : pos);
#pragma unroll
      for (int ni = 0; ni < 2; ++ni) {
        const int j = ni * 16 + (lane & 15);
        const float c = cosT[pos * 32 + j];
        const float s = sinT[pos * 32 + j];
        const float x1 = acc[mi][ni][r], x2 = acc[mi][ni + 2][r];
        const int colg = n0 + wn * 64 + ni * 16 + (lane & 15);
        qh[(size_t)rowg * 1024 + colg]      = f2bf((x1 * c - x2 * s) * 0.125f);
        qh[(size_t)rowg * 1024 + colg + 32] = f2bf((x2 * c + x1 * s) * 0.125f);
      }
    }
  }
}

// ---------------------------------------------------------------------------
// GEMM2: kvl = kv @ Wkv;  cols<1024 -> kh (RoPE, kv_pos), cols>=1024 -> vh
// M=1024 N=2048 K=1024
__global__ __launch_bounds__(256) void gemm_kv_kernel(
    const u16* __restrict__ A, const u16* __restrict__ Bt,
    u16* __restrict__ kh, u16* __restrict__ vh, const int* __restrict__ kpos,
    const float* __restrict__ cosT, const float* __restrict__ sinT) {
  GEMM_PROLOGUE();
  const int mb = blockIdx.x >> 4, nb = blockIdx.x & 15;
  const int m0 = mb * 128, n0 = nb * 128;
  gemm_core_128(A, Bt, 1024, m0, n0, acc, As, Bs);
  const int lane = threadIdx.x & 63;
  const int wv = threadIdx.x >> 6, wm = wv >> 1, wn = wv & 1;
  const bool isK = (n0 + wn * 64) < 1024;
#pragma unroll
  for (int mi = 0; mi < 4; ++mi) {
#pragma unroll
    for (int r = 0; r < 4; ++r) {
      const int rowg = m0 + wm * 64 + mi * 16 + (lane >> 4) * 4 + r;  // 0..1023
      if (isK) {
        int pos = kpos[rowg & 511];
        pos = pos < 0 ? 0 : (pos > 8191 ? 8191 : pos);
#pragma unroll
        for (int ni = 0; ni < 2; ++ni) {
          const int j = ni * 16 + (lane & 15);
          const float c = cosT[pos * 32 + j];
          const float s = sinT[pos * 32 + j];
          const float x1 = acc[mi][ni][r], x2 = acc[mi][ni + 2][r];
          const int colg = n0 + wn * 64 + ni * 16 + (lane & 15);
          kh[(size_t)rowg * 1024 + colg]      = f2bf(x1 * c - x2 * s);
          kh[(size_t)rowg * 1024 + colg + 32] = f2bf(x2 * c + x1 * s);
        }
      } else {
#pragma unroll
        for (int ni = 0; ni < 4; ++ni) {
          const int colg = n0 + wn * 64 + ni * 16 + (lane & 15);
          vh[(size_t)rowg * 1024 + colg - 1024] = f2bf(acc[mi][ni][r]);
        }
      }
    }
  }
}

// ---------------------------------------------------------------------------
// GEMM3: out_f32 = ctx @ Wo   M=8192 N=1024 K=1024
__global__ __launch_bounds__(256) void gemm_out_kernel(
    const u16* __restrict__ A, const u16* __restrict__ Bt,
    float* __restrict__ out) {
  GEMM_PROLOGUE();
  const int mb = blockIdx.x >> 3, nb = blockIdx.x & 7;
  const int m0 = mb * 128, n0 = nb * 128;
  gemm_core_128(A, Bt, 1024, m0, n0, acc, As, Bs);
  const int lane = threadIdx.x & 63;
  const int wv = threadIdx.x >> 6, wm = wv >> 1, wn = wv & 1;
#pragma unroll
  for (int mi = 0; mi < 4; ++mi) {
#pragma unroll
    for (int r = 0; r < 4; ++r) {
      const int rowg = m0 + wm * 64 + mi * 16 + (lane >> 4) * 4 + r;
#pragma unroll
      for (int ni = 0; ni < 4; ++ni) {
        const int colg = n0 + wn * 64 + ni * 16 + (lane & 15);
        out[(size_t)rowg * 1024 + colg] = acc[mi][ni][r];
      }
    }
  }
}

// ---------------------------------------------------------------------------
// Sparse attention: each query attends to k in [max(seg-4,0), seg] (<=5 keys).
// One wave per query row; lane covers 16 contiguous channels (head = lane>>2).
// qh is pre-scaled by 1/8 so logits are plain dots.
__global__ __launch_bounds__(256) void attn_kernel(
    const u16* __restrict__ qh, const u16* __restrict__ kh,
    const u16* __restrict__ vh, const int* __restrict__ seg_id,
    u16* __restrict__ ctx) {
  const int lane = threadIdx.x & 63;
  const int row = (blockIdx.x * 256 + threadIdx.x) >> 6;   // 0..8191
  const int b = row >> 12;
  const int sg = seg_id[row];
  const int kmin = sg > 4 ? sg - 4 : 0;

  const u16* qp = qh + (size_t)row * 1024 + lane * 16;
  const bhalf8 qa = *(const bhalf8*)qp;
  const bhalf8 qb = *(const bhalf8*)(qp + 8);
  float qv[16];
#pragma unroll
  for (int e = 0; e < 8; ++e) {
    qv[e] = bf2f((u16)qa[e]);
    qv[8 + e] = bf2f((u16)qb[e]);
  }

  float sc[5];
  float mx = -3.0e38f;
#pragma unroll
  for (int t = 0; t < 5; ++t) {
    const int k = kmin + t;                      // always in [0,511]
    const u16* kp = kh + (size_t)((b << 9) + k) * 1024 + lane * 16;
    const bhalf8 ka = *(const bhalf8*)kp;
    const bhalf8 kb = *(const bhalf8*)(kp + 8);
    float d = 0.f;
#pragma unroll
    for (int e = 0; e < 8; ++e)
      d += qv[e] * bf2f((u16)ka[e]) + qv[8 + e] * bf2f((u16)kb[e]);
    d += __shfl_xor(d, 1);
    d += __shfl_xor(d, 2);                       // sum over the 4 lanes of this head
    sc[t] = (k <= sg) ? d : -3.0e38f;
    mx = fmaxf(mx, sc[t]);
  }

  float den = 0.f;
  float o[16];
#pragma unroll
  for (int e = 0; e < 16; ++e) o[e] = 0.f;
#pragma unroll
  for (int t = 0; t < 5; ++t) {
    const float p = __expf(sc[t] - mx);          // masked -> exp(-huge) = 0
    den += p;
    const int k = kmin + t;
    const u16* vp = vh + (size_t)((b << 9) + k) * 1024 + lane * 16;
    const bhalf8 va = *(const bhalf8*)vp;
    const bhalf8 vb = *(const bhalf8*)(vp + 8);
#pragma unroll
    for (int e = 0; e < 8; ++e) {
      o[e] += p * bf2f((u16)va[e]);
      o[8 + e] += p * bf2f((u16)vb[e]);
    }
  }
  const float inv = 1.f / den;
  bhalf8 oa, ob;
#pragma unroll
  for (int e = 0; e < 8; ++e) {
    oa[e] = (short)f2bf(o[e] * inv);
    ob[e] = (short)f2bf(o[8 + e] * inv);
  }
  u16* cp = ctx + (size_t)row * 1024 + lane * 16;
  *(bhalf8*)cp = oa;
  *(bhalf8*)(cp + 8) = ob;
}

// ---------------------------------------------------------------------------
extern "C" void kernel_launch(void* const* d_in, const int* in_sizes, int n_in,
                              void* d_out, int out_size, void* d_ws, size_t ws_size,
                              hipStream_t stream) {
  const float* q   = (const float*)d_in[0];
  const float* kv  = (const float*)d_in[1];
  const int* qpos  = (const int*)d_in[2];
  const int* kpos  = (const int*)d_in[3];
  const int* seg   = (const int*)d_in[4];
  const float* Wq  = (const float*)d_in[5];
  const float* Wkv = (const float*)d_in[6];
  const float* Wo  = (const float*)d_in[7];
  float* out = (float*)d_out;

  // workspace carve-up (~67 MB total)
  char* w = (char*)d_ws;
  u16* qb    = (u16*)w; w += (size_t)8192 * 1024 * 2;
  u16* kvb   = (u16*)w; w += (size_t)1024 * 1024 * 2;
  u16* WqT   = (u16*)w; w += (size_t)1024 * 1024 * 2;
  u16* WkvT  = (u16*)w; w += (size_t)2048 * 1024 * 2;
  u16* WoT   = (u16*)w; w += (size_t)1024 * 1024 * 2;
  u16* qhB   = (u16*)w; w += (size_t)8192 * 1024 * 2;
  u16* khB   = (u16*)w; w += (size_t)1024 * 1024 * 2;
  u16* vhB   = (u16*)w; w += (size_t)1024 * 1024 * 2;
  u16* ctxB  = (u16*)w; w += (size_t)8192 * 1024 * 2;
  float* cosT = (float*)w; w += (size_t)8192 * 32 * 4;
  float* sinT = (float*)w; w += (size_t)8192 * 32 * 4;

  f32_to_bf16_kernel<<<2048, 256, 0, stream>>>(q, qb, 8192 * 1024 / 4);
  f32_to_bf16_kernel<<<1024, 256, 0, stream>>>(kv, kvb, 1024 * 1024 / 4);
  transpose_w_kernel<<<dim3(32, 32), dim3(32, 8), 0, stream>>>(Wq, WqT, 1024, 1024);
  transpose_w_kernel<<<dim3(64, 32), dim3(32, 8), 0, stream>>>(Wkv, WkvT, 1024, 2048);
  transpose_w_kernel<<<dim3(32, 32), dim3(32, 8), 0, stream>>>(Wo, WoT, 1024, 1024);
  rope_table_kernel<<<1024, 256, 0, stream>>>(cosT, sinT);

  gemm_qh_kernel<<<512, 256, 0, stream>>>(qb, WqT, qhB, qpos, cosT, sinT);
  gemm_kv_kernel<<<128, 256, 0, stream>>>(kvb, WkvT, khB, vhB, kpos, cosT, sinT);
  attn_kernel<<<2048, 256, 0, stream>>>(qhB, khB, vhB, seg, ctxB);
  gemm_out_kernel<<<512, 256, 0, stream>>>(ctxB, WoT, out);
}

// Round 2
// 107.181 us; speedup vs baseline: 1.1438x; 1.1438x over previous
//
#include <hip/hip_runtime.h>
#include <math.h>

// SegmentCausalCrossAttentionFlex on MI355X (gfx950)
// B=2, LQ=4096, LK=512, Q_DIM=KV_DIM=D_ATTN=1024, H=16, HD=64, LOOKBACK=4
// R2: 3-buffer counted-vmcnt pipelined GEMM core, XCD swizzle, fused preproc.

typedef unsigned short u16;
typedef __attribute__((ext_vector_type(8))) short bhalf8;   // 8 x bf16 (MFMA A/B frag)
typedef __attribute__((ext_vector_type(4))) float fvec4;    // MFMA C/D frag

__device__ __forceinline__ u16 f2bf(float f) {
  unsigned u = __float_as_uint(f);
  u += 0x7fffu + ((u >> 16) & 1u);      // round-to-nearest-even
  return (u16)(u >> 16);
}
__device__ __forceinline__ float bf2f(u16 h) {
  return __uint_as_float(((unsigned)h) << 16);
}

// ---------------------------------------------------------------------------
// Fused preprocessing: q f32->bf16 (2097152 float4), kv f32->bf16 (262144),
// rope tables cos/sin[pos][j] (262144 elems), all in one grid-stride kernel.
__global__ __launch_bounds__(256) void prep_kernel(
    const float* __restrict__ q, u16* __restrict__ qb,
    const float* __restrict__ kv, u16* __restrict__ kvb,
    float* __restrict__ cosT, float* __restrict__ sinT) {
  const int NQ4 = 2097152, NKV4 = 262144, NR = 262144;
  const int stride = gridDim.x * 256;
  for (int u = blockIdx.x * 256 + threadIdx.x; u < NQ4 + NKV4 + NR; u += stride) {
    if (u < NQ4) {
      const float4 v = ((const float4*)q)[u];
      ushort4 o;
      o.x = f2bf(v.x); o.y = f2bf(v.y); o.z = f2bf(v.z); o.w = f2bf(v.w);
      ((ushort4*)qb)[u] = o;
    } else if (u < NQ4 + NKV4) {
      const int i = u - NQ4;
      const float4 v = ((const float4*)kv)[i];
      ushort4 o;
      o.x = f2bf(v.x); o.y = f2bf(v.y); o.z = f2bf(v.z); o.w = f2bf(v.w);
      ((ushort4*)kvb)[i] = o;
    } else {
      const int i = u - NQ4 - NKV4;
      const int pos = i >> 5, j = i & 31;
      const float invf = expf(-(float)j * 0.28782313662425572f);  // ln(10000)/32
      float s, c;
      sincosf((float)pos * invf, &s, &c);
      cosT[i] = c;
      sinT[i] = s;
    }
  }
}

// ---------------------------------------------------------------------------
// All three W transposes in one kernel. W [K=1024][N] f32 -> Wt [N][1024] bf16.
// blocks: [0,1024) Wq (N=1024), [1024,3072) Wkv (N=2048), [3072,4096) Wo.
__global__ __launch_bounds__(256) void transpose_all_kernel(
    const float* __restrict__ Wq, const float* __restrict__ Wkv,
    const float* __restrict__ Wo, u16* __restrict__ WqT,
    u16* __restrict__ WkvT, u16* __restrict__ WoT) {
  __shared__ float tile[32][33];
  const int bid = blockIdx.x;
  const float* W;
  u16* Wt;
  int N, t;
  if (bid < 1024)      { W = Wq;  Wt = WqT;  N = 1024; t = bid; }
  else if (bid < 3072) { W = Wkv; Wt = WkvT; N = 2048; t = bid - 1024; }
  else                 { W = Wo;  Wt = WoT;  N = 1024; t = bid - 3072; }
  const int sh = (N >> 11) + 5;               // 1024->5, 2048->6
  const int n0 = (t & ((1 << sh) - 1)) << 5;
  const int k0 = (t >> sh) << 5;
  const int tx = threadIdx.x & 31, ty = threadIdx.x >> 5;
#pragma unroll
  for (int i = 0; i < 32; i += 8)
    tile[ty + i][tx] = W[(size_t)(k0 + ty + i) * N + n0 + tx];
  __syncthreads();
#pragma unroll
  for (int i = 0; i < 32; i += 8)
    Wt[(size_t)(n0 + ty + i) * 1024 + k0 + tx] = f2bf(tile[tx][ty + i]);
}

// ---------------------------------------------------------------------------
// Pipelined 128x128 GEMM tile core: C += A[M,1024] * Bt[N,1024]^T.
// 4 waves (2x2), each 64x64 = 4x4 frags, mfma 16x16x32, BK=32, K=1024.
// 3 LDS buffers, stage 2 tiles ahead, s_waitcnt vmcnt(4) (4 gload_lds/stage
// per thread: oldest stage complete, newest stays in flight), raw s_barrier.
// 16B-chunk XOR swizzle slot = g ^ ((row>>1)&3), same K-bijection both
// operands (MFMA contraction invariant).
__device__ __forceinline__ void gemm_core_128_db(
    const u16* __restrict__ A, const u16* __restrict__ Bt,
    int m0, int n0, fvec4 acc[4][4], u16* As, u16* Bs) {
  const int tid = threadIdx.x;
  const int lane = tid & 63;
  const int wv = tid >> 6, wm = wv >> 1, wn = wv & 1;

  int a_off[4], b_off[4];
#pragma unroll
  for (int i = 0; i < 4; ++i) {
    const int rA = wm * 64 + i * 16 + (lane & 15);
    a_off[i] = rA * 32 + (((lane >> 4) ^ ((rA >> 1) & 3)) << 3);
    const int rB = wn * 64 + i * 16 + (lane & 15);
    b_off[i] = rB * 32 + (((lane >> 4) ^ ((rB >> 1) & 3)) << 3);
  }
  const int i0 = tid, i1 = tid + 256;
  const int r0 = i0 >> 2, g0 = (i0 & 3) ^ ((r0 >> 1) & 3);
  const int r1 = i1 >> 2, g1 = (i1 & 3) ^ ((r1 >> 1) & 3);
  const u16* a0 = A + (size_t)(m0 + r0) * 1024 + g0 * 8;
  const u16* a1 = A + (size_t)(m0 + r1) * 1024 + g1 * 8;
  const u16* b0 = Bt + (size_t)(n0 + r0) * 1024 + g0 * 8;
  const u16* b1 = Bt + (size_t)(n0 + r1) * 1024 + g1 * 8;

#define STAGE_DB(buf, kk)                                                    \
  do {                                                                       \
    u16* As_ = As + (buf) * 4096;                                            \
    u16* Bs_ = Bs + (buf) * 4096;                                            \
    __builtin_amdgcn_global_load_lds(                                        \
        (__attribute__((address_space(1))) void*)(a0 + (kk)),                \
        (__attribute__((address_space(3))) void*)(As_ + i0 * 8), 16, 0, 0);  \
    __builtin_amdgcn_global_load_lds(                                        \
        (__attribute__((address_space(1))) void*)(a1 + (kk)),                \
        (__attribute__((address_space(3))) void*)(As_ + i1 * 8), 16, 0, 0);  \
    __builtin_amdgcn_global_load_lds(                                        \
        (__attribute__((address_space(1))) void*)(b0 + (kk)),                \
        (__attribute__((address_space(3))) void*)(Bs_ + i0 * 8), 16, 0, 0);  \
    __builtin_amdgcn_global_load_lds(                                        \
        (__attribute__((address_space(1))) void*)(b1 + (kk)),                \
        (__attribute__((address_space(3))) void*)(Bs_ + i1 * 8), 16, 0, 0);  \
  } while (0)

  // prologue: stage tiles 0 and 1; wait for tile 0 (vmcnt(4): 8 outstanding,
  // oldest 4 = tile 0 done, FIFO semantics).
  STAGE_DB(0, 0);
  STAGE_DB(1, 32);
  asm volatile("s_waitcnt vmcnt(4)" ::: "memory");
  __builtin_amdgcn_s_barrier();

#pragma unroll
  for (int t = 0; t < 32; ++t) {
    const int cur = t % 3;
    const int nx2 = (t + 2) % 3;
    const int k2 = t * 32 + 64;
    if (k2 < 1024) STAGE_DB(nx2, k2);
    const int co = cur * 4096;
    bhalf8 af[4], bfv[4];
#pragma unroll
    for (int i = 0; i < 4; ++i) af[i] = *(const bhalf8*)(As + co + a_off[i]);
#pragma unroll
    for (int i = 0; i < 4; ++i) bfv[i] = *(const bhalf8*)(Bs + co + b_off[i]);
    __builtin_amdgcn_s_setprio(1);
#pragma unroll
    for (int mi = 0; mi < 4; ++mi)
#pragma unroll
      for (int ni = 0; ni < 4; ++ni)
        acc[mi][ni] = __builtin_amdgcn_mfma_f32_16x16x32_bf16(
            af[mi], bfv[ni], acc[mi][ni], 0, 0, 0);
    __builtin_amdgcn_s_setprio(0);
    if (k2 < 1024) {
      asm volatile("s_waitcnt vmcnt(4)" ::: "memory");  // tile t+1 landed
    } else {
      asm volatile("s_waitcnt vmcnt(0)" ::: "memory");  // drain tail
    }
    __builtin_amdgcn_s_barrier();
  }
#undef STAGE_DB
}

#define GEMM_PROLOGUE()                                              \
  __shared__ __align__(16) u16 As[3 * 128 * 32];                     \
  __shared__ __align__(16) u16 Bs[3 * 128 * 32];                     \
  fvec4 acc[4][4];                                                   \
  _Pragma("unroll") for (int i = 0; i < 4; ++i)                      \
      _Pragma("unroll") for (int j = 0; j < 4; ++j)                  \
          acc[i][j] = (fvec4){0.f, 0.f, 0.f, 0.f};

// ---------------------------------------------------------------------------
// GEMM1: qh = bf16( RoPE(q @ Wq) * 0.125 )   M=8192 N=1024 K=1024, 512 wgs
__global__ __launch_bounds__(256) void gemm_qh_kernel(
    const u16* __restrict__ A, const u16* __restrict__ Bt,
    u16* __restrict__ qh, const int* __restrict__ pos_ids,
    const float* __restrict__ cosT, const float* __restrict__ sinT) {
  GEMM_PROLOGUE();
  const int wg = ((blockIdx.x & 7) << 6) + (blockIdx.x >> 3);  // XCD swizzle
  const int m0 = (wg >> 3) * 128, n0 = (wg & 7) * 128;
  gemm_core_128_db(A, Bt, m0, n0, acc, As, Bs);
  const int lane = threadIdx.x & 63;
  const int wv = threadIdx.x >> 6, wm = wv >> 1, wn = wv & 1;
#pragma unroll
  for (int mi = 0; mi < 4; ++mi) {
#pragma unroll
    for (int r = 0; r < 4; ++r) {
      const int rowg = m0 + wm * 64 + mi * 16 + (lane >> 4) * 4 + r;
      int pos = pos_ids[rowg];
      pos = pos < 0 ? 0 : (pos > 8191 ? 8191 : pos);
#pragma unroll
      for (int ni = 0; ni < 2; ++ni) {
        const int j = ni * 16 + (lane & 15);
        const float c = cosT[pos * 32 + j];
        const float s = sinT[pos * 32 + j];
        const float x1 = acc[mi][ni][r], x2 = acc[mi][ni + 2][r];
        const int colg = n0 + wn * 64 + ni * 16 + (lane & 15);
        qh[(size_t)rowg * 1024 + colg]      = f2bf((x1 * c - x2 * s) * 0.125f);
        qh[(size_t)rowg * 1024 + colg + 32] = f2bf((x2 * c + x1 * s) * 0.125f);
      }
    }
  }
}

// ---------------------------------------------------------------------------
// GEMM2: kvl = kv @ Wkv; cols<1024 -> kh (RoPE, kv_pos), cols>=1024 -> vh
// M=1024 N=2048 K=1024, 128 wgs
__global__ __launch_bounds__(256) void gemm_kv_kernel(
    const u16* __restrict__ A, const u16* __restrict__ Bt,
    u16* __restrict__ kh, u16* __restrict__ vh, const int* __restrict__ kpos,
    const float* __restrict__ cosT, const float* __restrict__ sinT) {
  GEMM_PROLOGUE();
  const int wg = ((blockIdx.x & 7) << 4) + (blockIdx.x >> 3);  // XCD swizzle
  const int m0 = (wg >> 4) * 128, n0 = (wg & 15) * 128;
  gemm_core_128_db(A, Bt, m0, n0, acc, As, Bs);
  const int lane = threadIdx.x & 63;
  const int wv = threadIdx.x >> 6, wm = wv >> 1, wn = wv & 1;
  const bool isK = (n0 + wn * 64) < 1024;
#pragma unroll
  for (int mi = 0; mi < 4; ++mi) {
#pragma unroll
    for (int r = 0; r < 4; ++r) {
      const int rowg = m0 + wm * 64 + mi * 16 + (lane >> 4) * 4 + r;  // 0..1023
      if (isK) {
        int pos = kpos[rowg & 511];
        pos = pos < 0 ? 0 : (pos > 8191 ? 8191 : pos);
#pragma unroll
        for (int ni = 0; ni < 2; ++ni) {
          const int j = ni * 16 + (lane & 15);
          const float c = cosT[pos * 32 + j];
          const float s = sinT[pos * 32 + j];
          const float x1 = acc[mi][ni][r], x2 = acc[mi][ni + 2][r];
          const int colg = n0 + wn * 64 + ni * 16 + (lane & 15);
          kh[(size_t)rowg * 1024 + colg]      = f2bf(x1 * c - x2 * s);
          kh[(size_t)rowg * 1024 + colg + 32] = f2bf(x2 * c + x1 * s);
        }
      } else {
#pragma unroll
        for (int ni = 0; ni < 4; ++ni) {
          const int colg = n0 + wn * 64 + ni * 16 + (lane & 15);
          vh[(size_t)rowg * 1024 + colg - 1024] = f2bf(acc[mi][ni][r]);
        }
      }
    }
  }
}

// ---------------------------------------------------------------------------
// GEMM3: out_f32 = ctx @ Wo   M=8192 N=1024 K=1024, 512 wgs
__global__ __launch_bounds__(256) void gemm_out_kernel(
    const u16* __restrict__ A, const u16* __restrict__ Bt,
    float* __restrict__ out) {
  GEMM_PROLOGUE();
  const int wg = ((blockIdx.x & 7) << 6) + (blockIdx.x >> 3);  // XCD swizzle
  const int m0 = (wg >> 3) * 128, n0 = (wg & 7) * 128;
  gemm_core_128_db(A, Bt, m0, n0, acc, As, Bs);
  const int lane = threadIdx.x & 63;
  const int wv = threadIdx.x >> 6, wm = wv >> 1, wn = wv & 1;
#pragma unroll
  for (int mi = 0; mi < 4; ++mi) {
#pragma unroll
    for (int r = 0; r < 4; ++r) {
      const int rowg = m0 + wm * 64 + mi * 16 + (lane >> 4) * 4 + r;
#pragma unroll
      for (int ni = 0; ni < 4; ++ni) {
        const int colg = n0 + wn * 64 + ni * 16 + (lane & 15);
        out[(size_t)rowg * 1024 + colg] = acc[mi][ni][r];
      }
    }
  }
}

// ---------------------------------------------------------------------------
// Sparse attention: each query attends to k in [max(seg-4,0), seg] (<=5 keys).
// One wave per query row; lane covers 16 contiguous channels (head = lane>>2).
// qh is pre-scaled by 1/8 so logits are plain dots.
__global__ __launch_bounds__(256) void attn_kernel(
    const u16* __restrict__ qh, const u16* __restrict__ kh,
    const u16* __restrict__ vh, const int* __restrict__ seg_id,
    u16* __restrict__ ctx) {
  const int lane = threadIdx.x & 63;
  const int row = (blockIdx.x * 256 + threadIdx.x) >> 6;   // 0..8191
  const int b = row >> 12;
  const int sg = seg_id[row];
  const int kmin = sg > 4 ? sg - 4 : 0;

  const u16* qp = qh + (size_t)row * 1024 + lane * 16;
  const bhalf8 qa = *(const bhalf8*)qp;
  const bhalf8 qb = *(const bhalf8*)(qp + 8);
  float qv[16];
#pragma unroll
  for (int e = 0; e < 8; ++e) {
    qv[e] = bf2f((u16)qa[e]);
    qv[8 + e] = bf2f((u16)qb[e]);
  }

  float sc[5];
  float mx = -3.0e38f;
#pragma unroll
  for (int t = 0; t < 5; ++t) {
    const int k = kmin + t;                      // always in [0,511]
    const u16* kp = kh + (size_t)((b << 9) + k) * 1024 + lane * 16;
    const bhalf8 ka = *(const bhalf8*)kp;
    const bhalf8 kb = *(const bhalf8*)(kp + 8);
    float d = 0.f;
#pragma unroll
    for (int e = 0; e < 8; ++e)
      d += qv[e] * bf2f((u16)ka[e]) + qv[8 + e] * bf2f((u16)kb[e]);
    d += __shfl_xor(d, 1);
    d += __shfl_xor(d, 2);                       // sum over 4 lanes of this head
    sc[t] = (k <= sg) ? d : -3.0e38f;
    mx = fmaxf(mx, sc[t]);
  }

  float den = 0.f;
  float o[16];
#pragma unroll
  for (int e = 0; e < 16; ++e) o[e] = 0.f;
#pragma unroll
  for (int t = 0; t < 5; ++t) {
    const float p = __expf(sc[t] - mx);          // masked -> exp(-huge) = 0
    den += p;
    const int k = kmin + t;
    const u16* vp = vh + (size_t)((b << 9) + k) * 1024 + lane * 16;
    const bhalf8 va = *(const bhalf8*)vp;
    const bhalf8 vb = *(const bhalf8*)(vp + 8);
#pragma unroll
    for (int e = 0; e < 8; ++e) {
      o[e] += p * bf2f((u16)va[e]);
      o[8 + e] += p * bf2f((u16)vb[e]);
    }
  }
  const float inv = 1.f / den;
  bhalf8 oa, ob;
#pragma unroll
  for (int e = 0; e < 8; ++e) {
    oa[e] = (short)f2bf(o[e] * inv);
    ob[e] = (short)f2bf(o[8 + e] * inv);
  }
  u16* cp = ctx + (size_t)row * 1024 + lane * 16;
  *(bhalf8*)cp = oa;
  *(bhalf8*)(cp + 8) = ob;
}

// ---------------------------------------------------------------------------
extern "C" void kernel_launch(void* const* d_in, const int* in_sizes, int n_in,
                              void* d_out, int out_size, void* d_ws, size_t ws_size,
                              hipStream_t stream) {
  const float* q   = (const float*)d_in[0];
  const float* kv  = (const float*)d_in[1];
  const int* qpos  = (const int*)d_in[2];
  const int* kpos  = (const int*)d_in[3];
  const int* seg   = (const int*)d_in[4];
  const float* Wq  = (const float*)d_in[5];
  const float* Wkv = (const float*)d_in[6];
  const float* Wo  = (const float*)d_in[7];
  float* out = (float*)d_out;

  // workspace carve-up (~67 MB total)
  char* w = (char*)d_ws;
  u16* qb    = (u16*)w; w += (size_t)8192 * 1024 * 2;
  u16* kvb   = (u16*)w; w += (size_t)1024 * 1024 * 2;
  u16* WqT   = (u16*)w; w += (size_t)1024 * 1024 * 2;
  u16* WkvT  = (u16*)w; w += (size_t)2048 * 1024 * 2;
  u16* WoT   = (u16*)w; w += (size_t)1024 * 1024 * 2;
  u16* qhB   = (u16*)w; w += (size_t)8192 * 1024 * 2;
  u16* khB   = (u16*)w; w += (size_t)1024 * 1024 * 2;
  u16* vhB   = (u16*)w; w += (size_t)1024 * 1024 * 2;
  u16* ctxB  = (u16*)w; w += (size_t)8192 * 1024 * 2;
  float* cosT = (float*)w; w += (size_t)8192 * 32 * 4;
  float* sinT = (float*)w; w += (size_t)8192 * 32 * 4;

  prep_kernel<<<2048, 256, 0, stream>>>(q, qb, kv, kvb, cosT, sinT);
  transpose_all_kernel<<<4096, 256, 0, stream>>>(Wq, Wkv, Wo, WqT, WkvT, WoT);

  gemm_kv_kernel<<<128, 256, 0, stream>>>(kvb, WkvT, khB, vhB, kpos, cosT, sinT);
  gemm_qh_kernel<<<512, 256, 0, stream>>>(qb, WqT, qhB, qpos, cosT, sinT);
  attn_kernel<<<2048, 256, 0, stream>>>(qhB, khB, vhB, seg, ctxB);
  gemm_out_kernel<<<512, 256, 0, stream>>>(ctxB, WoT, out);
}

// Round 3
// 92.439 us; speedup vs baseline: 1.3262x; 1.1595x over previous
//
#include <hip/hip_runtime.h>
#include <math.h>

// SegmentCausalCrossAttentionFlex on MI355X (gfx950)
// B=2, LQ=4096, LK=512, Q_DIM=KV_DIM=D_ATTN=1024, H=16, HD=64, LOOKBACK=4
// R3: fused preproc (transpose+cast+rope), fused kv+qh GEMM launch (full-chip
// concurrency), float2 rope table (4096 rows), same pipelined GEMM core.

typedef unsigned short u16;
typedef __attribute__((ext_vector_type(8))) short bhalf8;   // 8 x bf16 (MFMA A/B frag)
typedef __attribute__((ext_vector_type(4))) float fvec4;    // MFMA C/D frag

__device__ __forceinline__ u16 f2bf(float f) {
  unsigned u = __float_as_uint(f);
  u += 0x7fffu + ((u >> 16) & 1u);      // round-to-nearest-even
  return (u16)(u >> 16);
}
__device__ __forceinline__ float bf2f(u16 h) {
  return __uint_as_float(((unsigned)h) << 16);
}

// ---------------------------------------------------------------------------
// Fused preprocessing.
// blocks [0,4096): W transposes, [K=1024][N] f32 -> Wt [N][1024] bf16.
//   [0,1024) Wq (N=1024), [1024,3072) Wkv (N=2048), [3072,4096) Wo (N=1024)
// blocks [4096,6144): grid-stride: q cast (2097152 f4), kv cast (262144 f4),
//   rope table float2 {cos,sin}[pos<4096][j<32] (131072).
__global__ __launch_bounds__(256) void prep_kernel(
    const float* __restrict__ Wq, const float* __restrict__ Wkv,
    const float* __restrict__ Wo, u16* __restrict__ WqT,
    u16* __restrict__ WkvT, u16* __restrict__ WoT,
    const float* __restrict__ q, u16* __restrict__ qb,
    const float* __restrict__ kv, u16* __restrict__ kvb,
    float2* __restrict__ csT) {
  const int bid = blockIdx.x;
  if (bid < 4096) {
    __shared__ float tile[32][33];
    const float* W;
    u16* Wt;
    int N, t;
    if (bid < 1024)      { W = Wq;  Wt = WqT;  N = 1024; t = bid; }
    else if (bid < 3072) { W = Wkv; Wt = WkvT; N = 2048; t = bid - 1024; }
    else                 { W = Wo;  Wt = WoT;  N = 1024; t = bid - 3072; }
    const int sh = (N >> 11) + 5;               // 1024->5, 2048->6
    const int n0 = (t & ((1 << sh) - 1)) << 5;
    const int k0 = (t >> sh) << 5;
    const int tx = threadIdx.x & 31, ty = threadIdx.x >> 5;
#pragma unroll
    for (int i = 0; i < 32; i += 8)
      tile[ty + i][tx] = W[(size_t)(k0 + ty + i) * N + n0 + tx];
    __syncthreads();
#pragma unroll
    for (int i = 0; i < 32; i += 8)
      Wt[(size_t)(n0 + ty + i) * 1024 + k0 + tx] = f2bf(tile[tx][ty + i]);
    return;
  }
  const int NQ4 = 2097152, NKV4 = 262144, NR = 131072;
  const int stride = 2048 * 256;
  for (int u = (bid - 4096) * 256 + threadIdx.x; u < NQ4 + NKV4 + NR; u += stride) {
    if (u < NQ4) {
      const float4 v = ((const float4*)q)[u];
      ushort4 o;
      o.x = f2bf(v.x); o.y = f2bf(v.y); o.z = f2bf(v.z); o.w = f2bf(v.w);
      ((ushort4*)qb)[u] = o;
    } else if (u < NQ4 + NKV4) {
      const int i = u - NQ4;
      const float4 v = ((const float4*)kv)[i];
      ushort4 o;
      o.x = f2bf(v.x); o.y = f2bf(v.y); o.z = f2bf(v.z); o.w = f2bf(v.w);
      ((ushort4*)kvb)[i] = o;
    } else {
      const int i = u - NQ4 - NKV4;
      const int pos = i >> 5, j = i & 31;
      const float invf = expf(-(float)j * 0.28782313662425572f);  // ln(10000)/32
      float s, c;
      sincosf((float)pos * invf, &s, &c);
      csT[i] = make_float2(c, s);
    }
  }
}

// ---------------------------------------------------------------------------
// Pipelined 128x128 GEMM tile core: C += A[M,1024] * Bt[N,1024]^T.
// 4 waves (2x2), each 64x64 = 4x4 frags, mfma 16x16x32, BK=32, K=1024.
// 3 LDS buffers, stage 2 tiles ahead, s_waitcnt vmcnt(4), raw s_barrier.
// 16B-chunk XOR swizzle slot = g ^ ((row>>1)&3), same K-bijection both
// operands (MFMA contraction invariant).
__device__ __forceinline__ void gemm_core_128_db(
    const u16* __restrict__ A, const u16* __restrict__ Bt,
    int m0, int n0, fvec4 acc[4][4], u16* As, u16* Bs) {
  const int tid = threadIdx.x;
  const int lane = tid & 63;
  const int wv = tid >> 6, wm = wv >> 1, wn = wv & 1;

  int a_off[4], b_off[4];
#pragma unroll
  for (int i = 0; i < 4; ++i) {
    const int rA = wm * 64 + i * 16 + (lane & 15);
    a_off[i] = rA * 32 + (((lane >> 4) ^ ((rA >> 1) & 3)) << 3);
    const int rB = wn * 64 + i * 16 + (lane & 15);
    b_off[i] = rB * 32 + (((lane >> 4) ^ ((rB >> 1) & 3)) << 3);
  }
  const int i0 = tid, i1 = tid + 256;
  const int r0 = i0 >> 2, g0 = (i0 & 3) ^ ((r0 >> 1) & 3);
  const int r1 = i1 >> 2, g1 = (i1 & 3) ^ ((r1 >> 1) & 3);
  const u16* a0 = A + (size_t)(m0 + r0) * 1024 + g0 * 8;
  const u16* a1 = A + (size_t)(m0 + r1) * 1024 + g1 * 8;
  const u16* b0 = Bt + (size_t)(n0 + r0) * 1024 + g0 * 8;
  const u16* b1 = Bt + (size_t)(n0 + r1) * 1024 + g1 * 8;

#define STAGE_DB(buf, kk)                                                    \
  do {                                                                       \
    u16* As_ = As + (buf) * 4096;                                            \
    u16* Bs_ = Bs + (buf) * 4096;                                            \
    __builtin_amdgcn_global_load_lds(                                        \
        (__attribute__((address_space(1))) void*)(a0 + (kk)),                \
        (__attribute__((address_space(3))) void*)(As_ + i0 * 8), 16, 0, 0);  \
    __builtin_amdgcn_global_load_lds(                                        \
        (__attribute__((address_space(1))) void*)(a1 + (kk)),                \
        (__attribute__((address_space(3))) void*)(As_ + i1 * 8), 16, 0, 0);  \
    __builtin_amdgcn_global_load_lds(                                        \
        (__attribute__((address_space(1))) void*)(b0 + (kk)),                \
        (__attribute__((address_space(3))) void*)(Bs_ + i0 * 8), 16, 0, 0);  \
    __builtin_amdgcn_global_load_lds(                                        \
        (__attribute__((address_space(1))) void*)(b1 + (kk)),                \
        (__attribute__((address_space(3))) void*)(Bs_ + i1 * 8), 16, 0, 0);  \
  } while (0)

  // prologue: stage tiles 0 and 1; wait tile 0 (vmcnt(4): oldest 4 done).
  STAGE_DB(0, 0);
  STAGE_DB(1, 32);
  asm volatile("s_waitcnt vmcnt(4)" ::: "memory");
  __builtin_amdgcn_s_barrier();

#pragma unroll
  for (int t = 0; t < 32; ++t) {
    const int cur = t % 3;
    const int nx2 = (t + 2) % 3;
    const int k2 = t * 32 + 64;
    if (k2 < 1024) STAGE_DB(nx2, k2);
    const int co = cur * 4096;
    bhalf8 af[4], bfv[4];
#pragma unroll
    for (int i = 0; i < 4; ++i) af[i] = *(const bhalf8*)(As + co + a_off[i]);
#pragma unroll
    for (int i = 0; i < 4; ++i) bfv[i] = *(const bhalf8*)(Bs + co + b_off[i]);
    __builtin_amdgcn_s_setprio(1);
#pragma unroll
    for (int mi = 0; mi < 4; ++mi)
#pragma unroll
      for (int ni = 0; ni < 4; ++ni)
        acc[mi][ni] = __builtin_amdgcn_mfma_f32_16x16x32_bf16(
            af[mi], bfv[ni], acc[mi][ni], 0, 0, 0);
    __builtin_amdgcn_s_setprio(0);
    if (k2 < 1024) {
      asm volatile("s_waitcnt vmcnt(4)" ::: "memory");  // tile t+1 landed
    } else {
      asm volatile("s_waitcnt vmcnt(0)" ::: "memory");  // drain tail
    }
    __builtin_amdgcn_s_barrier();
  }
#undef STAGE_DB
}

#define GEMM_PROLOGUE()                                              \
  __shared__ __align__(16) u16 As[3 * 128 * 32];                     \
  __shared__ __align__(16) u16 Bs[3 * 128 * 32];                     \
  fvec4 acc[4][4];                                                   \
  _Pragma("unroll") for (int i = 0; i < 4; ++i)                      \
      _Pragma("unroll") for (int j = 0; j < 4; ++j)                  \
          acc[i][j] = (fvec4){0.f, 0.f, 0.f, 0.f};

// ---------------------------------------------------------------------------
// Fused GEMM1+GEMM2, 640 wgs (8 XCD chunks of 80).
// role swz<512:  qh = bf16( RoPE(q @ Wq) * 0.125 )   M=8192 N=1024
// role swz>=512: kvl = kv @ Wkv; cols<1024 -> kh (RoPE), cols>=1024 -> vh
__global__ __launch_bounds__(256) void gemm12_kernel(
    const u16* __restrict__ qA, const u16* __restrict__ WqT,
    const u16* __restrict__ kvA, const u16* __restrict__ WkvT,
    u16* __restrict__ qh, u16* __restrict__ kh, u16* __restrict__ vh,
    const int* __restrict__ qpos, const int* __restrict__ kpos,
    const float2* __restrict__ csT) {
  GEMM_PROLOGUE();
  const int swz = ((blockIdx.x & 7) * 80) + (blockIdx.x >> 3);  // bijective, 640=8*80
  const int lane = threadIdx.x & 63;
  const int wv = threadIdx.x >> 6, wm = wv >> 1, wn = wv & 1;

  if (swz < 512) {
    const int m0 = (swz >> 3) * 128, n0 = (swz & 7) * 128;
    gemm_core_128_db(qA, WqT, m0, n0, acc, As, Bs);
#pragma unroll
    for (int mi = 0; mi < 4; ++mi) {
#pragma unroll
      for (int r = 0; r < 4; ++r) {
        const int rowg = m0 + wm * 64 + mi * 16 + (lane >> 4) * 4 + r;
        int pos = qpos[rowg];
        pos = pos < 0 ? 0 : (pos > 4095 ? 4095 : pos);
#pragma unroll
        for (int ni = 0; ni < 2; ++ni) {
          const int j = ni * 16 + (lane & 15);
          const float2 cs = csT[pos * 32 + j];
          const float x1 = acc[mi][ni][r], x2 = acc[mi][ni + 2][r];
          const int colg = n0 + wn * 64 + ni * 16 + (lane & 15);
          qh[(size_t)rowg * 1024 + colg]      = f2bf((x1 * cs.x - x2 * cs.y) * 0.125f);
          qh[(size_t)rowg * 1024 + colg + 32] = f2bf((x2 * cs.x + x1 * cs.y) * 0.125f);
        }
      }
    }
  } else {
    const int t = swz - 512;                       // 0..127
    const int m0 = (t >> 4) * 128, n0 = (t & 15) * 128;
    gemm_core_128_db(kvA, WkvT, m0, n0, acc, As, Bs);
    const bool isK = (n0 + wn * 64) < 1024;
#pragma unroll
    for (int mi = 0; mi < 4; ++mi) {
#pragma unroll
      for (int r = 0; r < 4; ++r) {
        const int rowg = m0 + wm * 64 + mi * 16 + (lane >> 4) * 4 + r;  // 0..1023
        if (isK) {
          int pos = kpos[rowg & 511];
          pos = pos < 0 ? 0 : (pos > 4095 ? 4095 : pos);
#pragma unroll
          for (int ni = 0; ni < 2; ++ni) {
            const int j = ni * 16 + (lane & 15);
            const float2 cs = csT[pos * 32 + j];
            const float x1 = acc[mi][ni][r], x2 = acc[mi][ni + 2][r];
            const int colg = n0 + wn * 64 + ni * 16 + (lane & 15);
            kh[(size_t)rowg * 1024 + colg]      = f2bf(x1 * cs.x - x2 * cs.y);
            kh[(size_t)rowg * 1024 + colg + 32] = f2bf(x2 * cs.x + x1 * cs.y);
          }
        } else {
#pragma unroll
          for (int ni = 0; ni < 4; ++ni) {
            const int colg = n0 + wn * 64 + ni * 16 + (lane & 15);
            vh[(size_t)rowg * 1024 + colg - 1024] = f2bf(acc[mi][ni][r]);
          }
        }
      }
    }
  }
}

// ---------------------------------------------------------------------------
// GEMM3: out_f32 = ctx @ Wo   M=8192 N=1024 K=1024, 512 wgs
__global__ __launch_bounds__(256) void gemm_out_kernel(
    const u16* __restrict__ A, const u16* __restrict__ Bt,
    float* __restrict__ out) {
  GEMM_PROLOGUE();
  const int wg = ((blockIdx.x & 7) << 6) + (blockIdx.x >> 3);  // XCD swizzle
  const int m0 = (wg >> 3) * 128, n0 = (wg & 7) * 128;
  gemm_core_128_db(A, Bt, m0, n0, acc, As, Bs);
  const int lane = threadIdx.x & 63;
  const int wv = threadIdx.x >> 6, wm = wv >> 1, wn = wv & 1;
#pragma unroll
  for (int mi = 0; mi < 4; ++mi) {
#pragma unroll
    for (int r = 0; r < 4; ++r) {
      const int rowg = m0 + wm * 64 + mi * 16 + (lane >> 4) * 4 + r;
#pragma unroll
      for (int ni = 0; ni < 4; ++ni) {
        const int colg = n0 + wn * 64 + ni * 16 + (lane & 15);
        out[(size_t)rowg * 1024 + colg] = acc[mi][ni][r];
      }
    }
  }
}

// ---------------------------------------------------------------------------
// Sparse attention: each query attends to k in [max(seg-4,0), seg] (<=5 keys).
// One wave per query row; lane covers 16 contiguous channels (head = lane>>2).
// qh is pre-scaled by 1/8 so logits are plain dots.
__global__ __launch_bounds__(256) void attn_kernel(
    const u16* __restrict__ qh, const u16* __restrict__ kh,
    const u16* __restrict__ vh, const int* __restrict__ seg_id,
    u16* __restrict__ ctx) {
  const int lane = threadIdx.x & 63;
  const int row = (blockIdx.x * 256 + threadIdx.x) >> 6;   // 0..8191
  const int b = row >> 12;
  const int sg = seg_id[row];
  const int kmin = sg > 4 ? sg - 4 : 0;

  const u16* qp = qh + (size_t)row * 1024 + lane * 16;
  const bhalf8 qa = *(const bhalf8*)qp;
  const bhalf8 qb = *(const bhalf8*)(qp + 8);
  float qv[16];
#pragma unroll
  for (int e = 0; e < 8; ++e) {
    qv[e] = bf2f((u16)qa[e]);
    qv[8 + e] = bf2f((u16)qb[e]);
  }

  float sc[5];
  float mx = -3.0e38f;
#pragma unroll
  for (int t = 0; t < 5; ++t) {
    const int k = kmin + t;                      // always in [0,511]
    const u16* kp = kh + (size_t)((b << 9) + k) * 1024 + lane * 16;
    const bhalf8 ka = *(const bhalf8*)kp;
    const bhalf8 kb = *(const bhalf8*)(kp + 8);
    float d = 0.f;
#pragma unroll
    for (int e = 0; e < 8; ++e)
      d += qv[e] * bf2f((u16)ka[e]) + qv[8 + e] * bf2f((u16)kb[e]);
    d += __shfl_xor(d, 1);
    d += __shfl_xor(d, 2);                       // sum over 4 lanes of this head
    sc[t] = (k <= sg) ? d : -3.0e38f;
    mx = fmaxf(mx, sc[t]);
  }

  float den = 0.f;
  float o[16];
#pragma unroll
  for (int e = 0; e < 16; ++e) o[e] = 0.f;
#pragma unroll
  for (int t = 0; t < 5; ++t) {
    const float p = __expf(sc[t] - mx);          // masked -> exp(-huge) = 0
    den += p;
    const int k = kmin + t;
    const u16* vp = vh + (size_t)((b << 9) + k) * 1024 + lane * 16;
    const bhalf8 va = *(const bhalf8*)vp;
    const bhalf8 vb = *(const bhalf8*)(vp + 8);
#pragma unroll
    for (int e = 0; e < 8; ++e) {
      o[e] += p * bf2f((u16)va[e]);
      o[8 + e] += p * bf2f((u16)vb[e]);
    }
  }
  const float inv = 1.f / den;
  bhalf8 oa, ob;
#pragma unroll
  for (int e = 0; e < 8; ++e) {
    oa[e] = (short)f2bf(o[e] * inv);
    ob[e] = (short)f2bf(o[8 + e] * inv);
  }
  u16* cp = ctx + (size_t)row * 1024 + lane * 16;
  *(bhalf8*)cp = oa;
  *(bhalf8*)(cp + 8) = ob;
}

// ---------------------------------------------------------------------------
extern "C" void kernel_launch(void* const* d_in, const int* in_sizes, int n_in,
                              void* d_out, int out_size, void* d_ws, size_t ws_size,
                              hipStream_t stream) {
  const float* q   = (const float*)d_in[0];
  const float* kv  = (const float*)d_in[1];
  const int* qpos  = (const int*)d_in[2];
  const int* kpos  = (const int*)d_in[3];
  const int* seg   = (const int*)d_in[4];
  const float* Wq  = (const float*)d_in[5];
  const float* Wkv = (const float*)d_in[6];
  const float* Wo  = (const float*)d_in[7];
  float* out = (float*)d_out;

  // workspace carve-up (~66 MB total)
  char* w = (char*)d_ws;
  u16* qb    = (u16*)w; w += (size_t)8192 * 1024 * 2;
  u16* kvb   = (u16*)w; w += (size_t)1024 * 1024 * 2;
  u16* WqT   = (u16*)w; w += (size_t)1024 * 1024 * 2;
  u16* WkvT  = (u16*)w; w += (size_t)2048 * 1024 * 2;
  u16* WoT   = (u16*)w; w += (size_t)1024 * 1024 * 2;
  u16* qhB   = (u16*)w; w += (size_t)8192 * 1024 * 2;
  u16* khB   = (u16*)w; w += (size_t)1024 * 1024 * 2;
  u16* vhB   = (u16*)w; w += (size_t)1024 * 1024 * 2;
  u16* ctxB  = (u16*)w; w += (size_t)8192 * 1024 * 2;
  float2* csT = (float2*)w; w += (size_t)4096 * 32 * 8;

  prep_kernel<<<6144, 256, 0, stream>>>(Wq, Wkv, Wo, WqT, WkvT, WoT,
                                        q, qb, kv, kvb, csT);
  gemm12_kernel<<<640, 256, 0, stream>>>(qb, WqT, kvb, WkvT,
                                         qhB, khB, vhB, qpos, kpos, csT);
  attn_kernel<<<2048, 256, 0, stream>>>(qhB, khB, vhB, seg, ctxB);
  gemm_out_kernel<<<512, 256, 0, stream>>>(ctxB, WoT, out);
}